// Round 5
// baseline (525.182 us; speedup 1.0000x reference)
//
#include <hip/hip_runtime.h>
#include <hip/hip_bf16.h>
#include <math.h>

#define N_NODES 65536
#define NDIR 9
#define NEDGE 589824
#define NBINS (N_NODES*NDIR)        // bin = dst*9 + sel (contiguous per node)

typedef __attribute__((ext_vector_type(8))) short short8;
typedef __attribute__((ext_vector_type(4))) float f32x4;

__device__ inline float bf2f(unsigned short u){ return __uint_as_float(((unsigned int)u)<<16); }
__device__ inline unsigned short f2bf(float f){
  unsigned int x = __float_as_uint(f);
  x += 0x7fff + ((x>>16)&1);           // round-to-nearest-even
  return (unsigned short)(x>>16);
}
__device__ inline float elu1(float x){ return x>0.f ? x : expm1f(x); }

// ---- prep: fold BN scale into W, transpose to [n][k] bf16 ----
// Wt1 rows 0..1151 = conv1 dirs, rows 1152..1279 = W3*s3 (shortcut). Wt2 = conv2 dirs.
__global__ void prep_w(const float* __restrict__ W1, const float* __restrict__ W2,
                       const float* __restrict__ W3,
                       const float* __restrict__ g1, const float* __restrict__ rv1,
                       const float* __restrict__ g2, const float* __restrict__ rv2,
                       const float* __restrict__ g3, const float* __restrict__ rv3,
                       unsigned short* __restrict__ Wt1, unsigned short* __restrict__ Wt2){
  int idx = blockIdx.x*256 + threadIdx.x;
  const float eps = 1e-5f;
  if (idx < 1280*128) {
    int n = idx >> 7, k = idx & 127;
    float v;
    if (n < 1152) { int d = n >> 7, c = n & 127;
      float s = g1[c]*rsqrtf(rv1[c]+eps); v = W1[(d*128 + k)*128 + c] * s; }
    else { int c = n - 1152;
      float s = g3[c]*rsqrtf(rv3[c]+eps); v = W3[k*128 + c] * s; }
    Wt1[idx] = f2bf(v);
  } else {
    int j = idx - 1280*128;
    int n = j >> 7, k = j & 127;
    int d = n >> 7, c = n & 127;
    float s = g2[c]*rsqrtf(rv2[c]+eps);
    Wt2[j] = f2bf(W2[(d*128 + k)*128 + c] * s);
  }
}

__global__ void prep_bias(const float* b1,const float* g1,const float* be1,const float* rm1,const float* rv1,
                          const float* b2,const float* g2,const float* be2,const float* rm2,const float* rv2,
                          const float* b3,const float* g3,const float* be3,const float* rm3,const float* rv3,
                          float* bias1, float* bias2, float* bias3, float* s3v){
  int c = threadIdx.x;
  const float eps = 1e-5f;
  float s1 = g1[c]*rsqrtf(rv1[c]+eps);
  bias1[c] = (b1[c]-rm1[c])*s1 + be1[c];
  float s2 = g2[c]*rsqrtf(rv2[c]+eps);
  bias2[c] = (b2[c]-rm2[c])*s2 + be2[c];
  float s3 = g3[c]*rsqrtf(rv3[c]+eps);
  bias3[c] = (b3[c]-rm3[c])*s3 + be3[c];   // s3 itself folded into Wt3
  s3v[c] = s3;
}

// ---- cast x to bf16 once ----
__global__ void xcast_k(const float* __restrict__ x, unsigned short* __restrict__ xb){
  int i = (blockIdx.x*256 + threadIdx.x)*8;
  f32x4 f0 = *(const f32x4*)(x + i);
  f32x4 f1 = *(const f32x4*)(x + i + 4);
  short8 t;
  #pragma unroll
  for (int j = 0; j < 4; j++){ t[j] = (short)f2bf(f0[j]); t[4+j] = (short)f2bf(f1[j]); }
  *(short8*)(xb + i) = t;
}

// ---- CSR build over (dst,sel) bins, bin = dst*9+sel ----
__global__ void hist_k(const int* __restrict__ dst, const int* __restrict__ sel,
                       int* __restrict__ hist){
  int e = blockIdx.x*256 + threadIdx.x;
  atomicAdd(&hist[dst[e]*9 + sel[e]], 1);
}

// exclusive scan of 1024 ints per block; block total -> bsum[blockIdx]
__global__ void scan1_k(const int* __restrict__ in, int* __restrict__ out, int* __restrict__ bsum){
  __shared__ int wsum[4];
  int t = threadIdx.x;
  int base = blockIdx.x*1024 + t*4;
  int4 v = *(const int4*)(in + base);
  int s = v.x + v.y + v.z + v.w;
  int lane = t & 63, w = t >> 6;
  int inc = s;
  #pragma unroll
  for (int o = 1; o < 64; o <<= 1){ int n = __shfl_up(inc, o); if (lane >= o) inc += n; }
  if (lane == 63) wsum[w] = inc;
  __syncthreads();
  int acc = 0;
  for (int i = 0; i < w; i++) acc += wsum[i];
  int ex = acc + inc - s;
  out[base] = ex; out[base+1] = ex + v.x; out[base+2] = ex + v.x + v.y; out[base+3] = ex + v.x + v.y + v.z;
  if (t == 255) bsum[blockIdx.x] = acc + inc;
}

__global__ void scan3_k(int* __restrict__ rs, const int* __restrict__ bsumx, int* __restrict__ cursor){
  int i = blockIdx.x*256 + threadIdx.x;
  int v = rs[i] + bsumx[i >> 10];
  rs[i] = v; cursor[i] = v;
  if (i == 0) rs[NBINS] = NEDGE;        // sentinel: end(bin b) == rs[b+1]
}

__global__ void scatter_k(const int* __restrict__ src, const int* __restrict__ dst,
                          const int* __restrict__ sel,
                          int* __restrict__ cursor, int* __restrict__ sorted){
  int e = blockIdx.x*256 + threadIdx.x;
  int bin = dst[e]*9 + sel[e];
  int pos = atomicAdd(&cursor[bin], 1);
  sorted[pos] = src[e];
}

// ---- fused layer v4: wave-autonomous 16-node tiles, register-direct A-fragments.
// Zero barriers, zero LDS. Lane l covers A-row (l&15), k-chunk (l>>4):
// per edge, 4 independent 16B loads land directly in the 4 MFMA A-fragments
// (fp32 accumulate, one bf16 round per dir -- numerically identical to v1).
// Wave then runs 8 col-tiles x 4 k-steps = 32 MFMAs per dir itself.
template<int IS_L2>
__global__ __launch_bounds__(256, 4) void layer_k(
    const unsigned short* __restrict__ H,     // layer input activations [N][128] bf16
    const unsigned short* __restrict__ X,     // xb (shortcut input, L2 only)
    const unsigned short* __restrict__ Wf,    // [1152][128] folded dir weights
    const unsigned short* __restrict__ W3f,   // [128][128] folded shortcut weights (L2)
    const int* __restrict__ rs, const int* __restrict__ sorted,
    const float* __restrict__ biasA, const float* __restrict__ bias3,
    const float* __restrict__ s3v,
    unsigned short* __restrict__ outB, float* __restrict__ outF){
  const int tid = threadIdx.x;
  const int wv = tid >> 6, l = tid & 63;
  const int r = l & 15, g = l >> 4;           // A-row in tile, 8-elem k-chunk group
  const int m0 = (blockIdx.x*4 + wv)*16;      // this wave's 16-node tile
  const int row = m0 + r;
  const int binb = row*9;

  f32x4 accC[8];
  #pragma unroll
  for (int ct = 0; ct < 8; ct++) accC[ct] = (f32x4){0,0,0,0};

  #pragma unroll 1
  for (int d = 0; d < 9; d++){
    // gather: fp32 accumulate this row's bin directly into A-fragment slots
    float aA[4][8];
    #pragma unroll
    for (int kk = 0; kk < 4; kk++)
      #pragma unroll
      for (int j = 0; j < 8; j++) aA[kk][j] = 0.f;

    int s = rs[binb + d], e = rs[binb + d + 1];
    for (int i = s; i < e; ++i){
      int key = sorted[i];
      const unsigned short* hp = H + (size_t)key*128 + g*8;
      short8 v0 = *(const short8*)(hp);
      short8 v1 = *(const short8*)(hp + 32);
      short8 v2 = *(const short8*)(hp + 64);
      short8 v3 = *(const short8*)(hp + 96);
      #pragma unroll
      for (int j = 0; j < 8; j++){
        aA[0][j] += bf2f((unsigned short)v0[j]);
        aA[1][j] += bf2f((unsigned short)v1[j]);
        aA[2][j] += bf2f((unsigned short)v2[j]);
        aA[3][j] += bf2f((unsigned short)v3[j]);
      }
    }
    short8 af[4];
    #pragma unroll
    for (int kk = 0; kk < 4; kk++)
      #pragma unroll
      for (int j = 0; j < 8; j++) af[kk][j] = (short)f2bf(aA[kk][j]);

    // MFMA: 8 col-tiles x 4 k-steps; B-frag lane = col (ct*16 + r), k-chunk g
    const unsigned short* Wd = Wf + (size_t)d*16384 + (size_t)r*128 + g*8;
    #pragma unroll
    for (int ct = 0; ct < 8; ct++){
      const unsigned short* wp = Wd + ct*16*128;
      #pragma unroll
      for (int kk = 0; kk < 4; kk++){
        short8 bfr = *(const short8*)(wp + kk*32);
        accC[ct] = __builtin_amdgcn_mfma_f32_16x16x32_bf16(af[kk], bfr, accC[ct], 0, 0, 0);
      }
    }
  }

  if constexpr (!IS_L2){
    #pragma unroll
    for (int ct = 0; ct < 8; ct++){
      int col = ct*16 + r;
      float bA = biasA[col];
      #pragma unroll
      for (int rr = 0; rr < 4; rr++){
        int orow = m0 + g*4 + rr;
        outB[(size_t)orow*128 + col] = f2bf(elu1(accC[ct][rr] + bA));
      }
    }
  } else {
    // phase 10: shortcut -- gather sel==0 edges from X, MFMA with W3f
    float aA[4][8];
    #pragma unroll
    for (int kk = 0; kk < 4; kk++)
      #pragma unroll
      for (int j = 0; j < 8; j++) aA[kk][j] = 0.f;
    int s = rs[binb], e = rs[binb + 1];
    for (int i = s; i < e; ++i){
      int key = sorted[i];
      const unsigned short* xp = X + (size_t)key*128 + g*8;
      short8 v0 = *(const short8*)(xp);
      short8 v1 = *(const short8*)(xp + 32);
      short8 v2 = *(const short8*)(xp + 64);
      short8 v3 = *(const short8*)(xp + 96);
      #pragma unroll
      for (int j = 0; j < 8; j++){
        aA[0][j] += bf2f((unsigned short)v0[j]);
        aA[1][j] += bf2f((unsigned short)v1[j]);
        aA[2][j] += bf2f((unsigned short)v2[j]);
        aA[3][j] += bf2f((unsigned short)v3[j]);
      }
    }
    short8 af[4];
    #pragma unroll
    for (int kk = 0; kk < 4; kk++)
      #pragma unroll
      for (int j = 0; j < 8; j++) af[kk][j] = (short)f2bf(aA[kk][j]);

    f32x4 sca[8];
    #pragma unroll
    for (int ct = 0; ct < 8; ct++) sca[ct] = (f32x4){0,0,0,0};
    const unsigned short* W3b = W3f + (size_t)r*128 + g*8;
    #pragma unroll
    for (int ct = 0; ct < 8; ct++){
      const unsigned short* wp = W3b + ct*16*128;
      #pragma unroll
      for (int kk = 0; kk < 4; kk++){
        short8 bfr = *(const short8*)(wp + kk*32);
        sca[ct] = __builtin_amdgcn_mfma_f32_16x16x32_bf16(af[kk], bfr, sca[ct], 0, 0, 0);
      }
    }
    #pragma unroll
    for (int ct = 0; ct < 8; ct++){
      int col = ct*16 + r;
      float bA = biasA[col], b3 = bias3[col], s3 = s3v[col];
      #pragma unroll
      for (int rr = 0; rr < 4; rr++){
        int orow = m0 + g*4 + rr;
        float h = elu1(accC[ct][rr] + bA);
        outF[(size_t)orow*128 + col] = elu1(h*s3 + sca[ct][rr] + b3);
      }
    }
  }
}

extern "C" void kernel_launch(void* const* d_in, const int* in_sizes, int n_in,
                              void* d_out, int out_size, void* d_ws, size_t ws_size,
                              hipStream_t stream){
  const float* x   = (const float*)d_in[0];
  const int*   ei  = (const int*)d_in[1];
  const int*   sel = (const int*)d_in[2];
  const float* W1  = (const float*)d_in[3];
  const float* b1  = (const float*)d_in[4];
  const float* g1  = (const float*)d_in[5];
  const float* be1 = (const float*)d_in[6];
  const float* rm1 = (const float*)d_in[7];
  const float* rv1 = (const float*)d_in[8];
  const float* W2  = (const float*)d_in[9];
  const float* b2  = (const float*)d_in[10];
  const float* g2  = (const float*)d_in[11];
  const float* be2 = (const float*)d_in[12];
  const float* rm2 = (const float*)d_in[13];
  const float* rv2 = (const float*)d_in[14];
  const float* W3  = (const float*)d_in[15];
  const float* b3  = (const float*)d_in[16];
  const float* g3  = (const float*)d_in[17];
  const float* be3 = (const float*)d_in[18];
  const float* rm3 = (const float*)d_in[19];
  const float* rv3 = (const float*)d_in[20];

  char* ws = (char*)d_ws;
  unsigned short* xb   = (unsigned short*)(ws);                  // 16.78 MB
  unsigned short* h1   = (unsigned short*)(ws + 16777216);       // 16.78 MB
  unsigned short* Wt1  = (unsigned short*)(ws + 33554432);       // 327,680 B (incl. W3fold @ rows 1152+)
  unsigned short* Wt2  = (unsigned short*)(ws + 33882112);       // 294,912 B
  float* bias1  = (float*)(ws + 34177024);
  float* bias2  = bias1 + 128;
  float* bias3  = bias1 + 256;
  float* s3v    = bias1 + 384;
  int* hist     = (int*)(ws + 34179072);                         // NBINS*4 = 2.36 MB
  int* rs       = (int*)(ws + 36538368);                         // (NBINS+1)*4
  int* cursor   = (int*)(ws + 38897920);                         // NBINS*4
  int* bsum     = (int*)(ws + 41257216);                         // 4 KB
  int* bsumx    = (int*)(ws + 41261312);                         // 4 KB
  int* bsumT    = (int*)(ws + 41265408);                         // 16 B
  int* sorted   = (int*)(ws + 41265664);                         // NBINS*4; end ~43.6 MB

  const int* srcp = ei;
  const int* dstp = ei + NEDGE;

  hipMemsetAsync(hist, 0, NBINS*sizeof(int), stream);
  prep_w<<<1216, 256, 0, stream>>>(W1, W2, W3, g1, rv1, g2, rv2, g3, rv3, Wt1, Wt2);
  prep_bias<<<1, 128, 0, stream>>>(b1,g1,be1,rm1,rv1, b2,g2,be2,rm2,rv2, b3,g3,be3,rm3,rv3,
                                   bias1, bias2, bias3, s3v);
  xcast_k<<<4096, 256, 0, stream>>>(x, xb);
  hist_k<<<NEDGE/256, 256, 0, stream>>>(dstp, sel, hist);
  scan1_k<<<NBINS/1024, 256, 0, stream>>>(hist, rs, bsum);       // 576 blocks
  scan1_k<<<1, 256, 0, stream>>>(bsum, bsumx, bsumT);            // scan 576 block sums (tail garbage harmless)
  scan3_k<<<NBINS/256, 256, 0, stream>>>(rs, bsumx, cursor);
  scatter_k<<<NEDGE/256, 256, 0, stream>>>(srcp, dstp, sel, cursor, sorted);

  layer_k<0><<<1024, 256, 0, stream>>>(xb, nullptr, Wt1, nullptr, rs, sorted,
                                       bias1, nullptr, nullptr, h1, nullptr);
  layer_k<1><<<1024, 256, 0, stream>>>(h1, xb, Wt2, Wt1 + 1152*128, rs, sorted,
                                       bias2, bias3, s3v, nullptr, (float*)d_out);
}

// Round 6
// 382.493 us; speedup vs baseline: 1.3731x; 1.3731x over previous
//
#include <hip/hip_runtime.h>
#include <hip/hip_bf16.h>
#include <math.h>

#define N_NODES 65536
#define NDIR 9
#define NEDGE 589824
#define NBINS (N_NODES*NDIR)        // bin = dst*9 + sel (contiguous per node)
#define TILE_M 32
#define SKEY_CAP 384
#define APITCH 136

typedef __attribute__((ext_vector_type(8))) short short8;
typedef __attribute__((ext_vector_type(4))) float f32x4;

__device__ inline float bf2f(unsigned short u){ return __uint_as_float(((unsigned int)u)<<16); }
__device__ inline unsigned short f2bf(float f){
  unsigned int x = __float_as_uint(f);
  x += 0x7fff + ((x>>16)&1);           // round-to-nearest-even
  return (unsigned short)(x>>16);
}
__device__ inline float elu1(float x){ return x>0.f ? x : expm1f(x); }

// ---- prep: fold BN scale into W, transpose to [n][k] bf16 ----
// Wt1 rows 0..1151 = conv1 dirs, rows 1152..1279 = W3*s3 (shortcut). Wt2 = conv2 dirs.
__global__ void prep_w(const float* __restrict__ W1, const float* __restrict__ W2,
                       const float* __restrict__ W3,
                       const float* __restrict__ g1, const float* __restrict__ rv1,
                       const float* __restrict__ g2, const float* __restrict__ rv2,
                       const float* __restrict__ g3, const float* __restrict__ rv3,
                       unsigned short* __restrict__ Wt1, unsigned short* __restrict__ Wt2){
  int idx = blockIdx.x*256 + threadIdx.x;
  const float eps = 1e-5f;
  if (idx < 1280*128) {
    int n = idx >> 7, k = idx & 127;
    float v;
    if (n < 1152) { int d = n >> 7, c = n & 127;
      float s = g1[c]*rsqrtf(rv1[c]+eps); v = W1[(d*128 + k)*128 + c] * s; }
    else { int c = n - 1152;
      float s = g3[c]*rsqrtf(rv3[c]+eps); v = W3[k*128 + c] * s; }
    Wt1[idx] = f2bf(v);
  } else {
    int j = idx - 1280*128;
    int n = j >> 7, k = j & 127;
    int d = n >> 7, c = n & 127;
    float s = g2[c]*rsqrtf(rv2[c]+eps);
    Wt2[j] = f2bf(W2[(d*128 + k)*128 + c] * s);
  }
}

__global__ void prep_bias(const float* b1,const float* g1,const float* be1,const float* rm1,const float* rv1,
                          const float* b2,const float* g2,const float* be2,const float* rm2,const float* rv2,
                          const float* b3,const float* g3,const float* be3,const float* rm3,const float* rv3,
                          float* bias1, float* bias2, float* bias3, float* s3v){
  int c = threadIdx.x;
  const float eps = 1e-5f;
  float s1 = g1[c]*rsqrtf(rv1[c]+eps);
  bias1[c] = (b1[c]-rm1[c])*s1 + be1[c];
  float s2 = g2[c]*rsqrtf(rv2[c]+eps);
  bias2[c] = (b2[c]-rm2[c])*s2 + be2[c];
  float s3 = g3[c]*rsqrtf(rv3[c]+eps);
  bias3[c] = (b3[c]-rm3[c])*s3 + be3[c];   // s3 itself folded into Wt3
  s3v[c] = s3;
}

// ---- cast x to bf16 once ----
__global__ void xcast_k(const float* __restrict__ x, unsigned short* __restrict__ xb){
  int i = (blockIdx.x*256 + threadIdx.x)*8;
  f32x4 f0 = *(const f32x4*)(x + i);
  f32x4 f1 = *(const f32x4*)(x + i + 4);
  short8 t;
  #pragma unroll
  for (int j = 0; j < 4; j++){ t[j] = (short)f2bf(f0[j]); t[4+j] = (short)f2bf(f1[j]); }
  *(short8*)(xb + i) = t;
}

// ---- CSR build over (dst,sel) bins, bin = dst*9+sel ----
__global__ void hist_k(const int* __restrict__ dst, const int* __restrict__ sel,
                       int* __restrict__ hist){
  int e = blockIdx.x*256 + threadIdx.x;
  atomicAdd(&hist[dst[e]*9 + sel[e]], 1);
}

// exclusive scan of 1024 ints per block; block total -> bsum[blockIdx]
__global__ void scan1_k(const int* __restrict__ in, int* __restrict__ out, int* __restrict__ bsum){
  __shared__ int wsum[4];
  int t = threadIdx.x;
  int base = blockIdx.x*1024 + t*4;
  int4 v = *(const int4*)(in + base);
  int s = v.x + v.y + v.z + v.w;
  int lane = t & 63, w = t >> 6;
  int inc = s;
  #pragma unroll
  for (int o = 1; o < 64; o <<= 1){ int n = __shfl_up(inc, o); if (lane >= o) inc += n; }
  if (lane == 63) wsum[w] = inc;
  __syncthreads();
  int acc = 0;
  for (int i = 0; i < w; i++) acc += wsum[i];
  int ex = acc + inc - s;
  out[base] = ex; out[base+1] = ex + v.x; out[base+2] = ex + v.x + v.y; out[base+3] = ex + v.x + v.y + v.z;
  if (t == 255) bsum[blockIdx.x] = acc + inc;
}

__global__ void scan3_k(int* __restrict__ rs, const int* __restrict__ bsumx, int* __restrict__ cursor){
  int i = blockIdx.x*256 + threadIdx.x;
  int v = rs[i] + bsumx[i >> 10];
  rs[i] = v; cursor[i] = v;
  if (i == 0) rs[NBINS] = NEDGE;        // sentinel: end(bin b) == rs[b+1]
}

__global__ void scatter_k(const int* __restrict__ src, const int* __restrict__ dst,
                          const int* __restrict__ sel,
                          int* __restrict__ cursor, int* __restrict__ sorted){
  int e = blockIdx.x*256 + threadIdx.x;
  int bin = dst[e]*9 + sel[e];
  int pos = atomicAdd(&cursor[bin], 1);
  sorted[pos] = src[e];
}

// ---- MFMA: wave computes all 32 rows x 32 cols (cols [w*32,w*32+32)) ----
__device__ __forceinline__ void mfma_tile(f32x4 acc[2][2],
                                          const unsigned short* agg,
                                          const unsigned short* __restrict__ Wd,
                                          int w, int q, int r){
  #pragma unroll
  for (int kk = 0; kk < 4; kk++){
    const unsigned short* wp = Wd + (size_t)(w*32 + r)*128 + kk*32 + q*8;
    short8 b0 = *(const short8*)wp;
    short8 b1 = *(const short8*)(wp + 16*128);
    #pragma unroll
    for (int mt = 0; mt < 2; mt++){
      short8 av = *(const short8*)&agg[(mt*16 + r)*APITCH + kk*32 + q*8];
      acc[mt][0] = __builtin_amdgcn_mfma_f32_16x16x32_bf16(av, b0, acc[mt][0], 0, 0, 0);
      acc[mt][1] = __builtin_amdgcn_mfma_f32_16x16x32_bf16(av, b1, acc[mt][1], 0, 0, 0);
    }
  }
}

// ---- fused layer v5: v1's residency envelope (256 thr, 8 blocks/CU) +
// 2-stream interleaved gather (rows rid & rid+16 together) +
// double-buffered agg -> ONE barrier per dir phase.
template<int IS_L2>
__global__ __launch_bounds__(256, 8) void layer_k(
    const unsigned short* __restrict__ H,     // layer input activations [N][128] bf16
    const unsigned short* __restrict__ X,     // xb (shortcut input, L2 only)
    const unsigned short* __restrict__ Wf,    // [1152][128] folded dir weights
    const unsigned short* __restrict__ W3f,   // [128][128] folded shortcut weights (L2)
    const int* __restrict__ rs, const int* __restrict__ sorted,
    const float* __restrict__ biasA, const float* __restrict__ bias3,
    const float* __restrict__ s3v,
    unsigned short* __restrict__ outB, float* __restrict__ outF){
  __shared__ __align__(16) unsigned short agg[2][TILE_M*APITCH]; // 17.4 KB dbuf
  __shared__ int skey[SKEY_CAP];                                 // 1.5 KB block edge keys
  __shared__ int rsl[TILE_M*9 + 1];                              // block bin offsets
  const int tid = threadIdx.x;
  const int w = tid >> 6, lane = tid & 63;
  const int q = lane >> 4, r = lane & 15;
  const int rid = tid >> 4, c = tid & 15;     // 16 lanes per row, 16B chunk c
  const int m0 = blockIdx.x * TILE_M;

  for (int i = tid; i <= TILE_M*9; i += 256) rsl[i] = rs[m0*9 + i];
  __syncthreads();
  const int lo = rsl[0];
  const int cnt = rsl[TILE_M*9] - lo;
  for (int i = tid; i < cnt && i < SKEY_CAP; i += 256) skey[i] = sorted[lo + i];
  __syncthreads();                     // skey ready

  f32x4 acc[2][2];
  #pragma unroll
  for (int mt = 0; mt < 2; mt++){ acc[mt][0] = (f32x4){0,0,0,0}; acc[mt][1] = (f32x4){0,0,0,0}; }

  #pragma unroll 1
  for (int d = 0; d < 9; d++){
    unsigned short* buf = agg[d & 1];
    // 2-stream gather: rows rid and rid+16 interleaved (two independent chains)
    {
      int bA = rid*9 + d, bB = (16 + rid)*9 + d;
      int sA = rsl[bA] - lo, eA = rsl[bA+1] - lo;
      int sB = rsl[bB] - lo, eB = rsl[bB+1] - lo;
      f32x4 aA0 = (f32x4){0,0,0,0}, aA1 = (f32x4){0,0,0,0};
      f32x4 aB0 = (f32x4){0,0,0,0}, aB1 = (f32x4){0,0,0,0};
      int lenA = eA - sA, lenB = eB - sB;
      int n = lenA > lenB ? lenA : lenB;
      for (int it = 0; it < n; it++){
        int iA = sA + it, iB = sB + it;
        bool dA = iA < eA, dB = iB < eB;
        int kA = dA ? ((iA < SKEY_CAP) ? skey[iA] : sorted[lo + iA]) : 0;
        int kB = dB ? ((iB < SKEY_CAP) ? skey[iB] : sorted[lo + iB]) : 0;
        short8 vA = *(const short8*)(H + (size_t)kA*128 + c*8);
        short8 vB = *(const short8*)(H + (size_t)kB*128 + c*8);
        if (dA){
          aA0[0] += bf2f((unsigned short)vA[0]); aA0[1] += bf2f((unsigned short)vA[1]);
          aA0[2] += bf2f((unsigned short)vA[2]); aA0[3] += bf2f((unsigned short)vA[3]);
          aA1[0] += bf2f((unsigned short)vA[4]); aA1[1] += bf2f((unsigned short)vA[5]);
          aA1[2] += bf2f((unsigned short)vA[6]); aA1[3] += bf2f((unsigned short)vA[7]);
        }
        if (dB){
          aB0[0] += bf2f((unsigned short)vB[0]); aB0[1] += bf2f((unsigned short)vB[1]);
          aB0[2] += bf2f((unsigned short)vB[2]); aB0[3] += bf2f((unsigned short)vB[3]);
          aB1[0] += bf2f((unsigned short)vB[4]); aB1[1] += bf2f((unsigned short)vB[5]);
          aB1[2] += bf2f((unsigned short)vB[6]); aB1[3] += bf2f((unsigned short)vB[7]);
        }
      }
      short8 oA;
      oA[0]=(short)f2bf(aA0[0]); oA[1]=(short)f2bf(aA0[1]); oA[2]=(short)f2bf(aA0[2]); oA[3]=(short)f2bf(aA0[3]);
      oA[4]=(short)f2bf(aA1[0]); oA[5]=(short)f2bf(aA1[1]); oA[6]=(short)f2bf(aA1[2]); oA[7]=(short)f2bf(aA1[3]);
      *(short8*)&buf[rid*APITCH + c*8] = oA;
      short8 oB;
      oB[0]=(short)f2bf(aB0[0]); oB[1]=(short)f2bf(aB0[1]); oB[2]=(short)f2bf(aB0[2]); oB[3]=(short)f2bf(aB0[3]);
      oB[4]=(short)f2bf(aB1[0]); oB[5]=(short)f2bf(aB1[1]); oB[6]=(short)f2bf(aB1[2]); oB[7]=(short)f2bf(aB1[3]);
      *(short8*)&buf[(16 + rid)*APITCH + c*8] = oB;
    }
    __syncthreads();                   // buf complete; dbuf makes one barrier sufficient
    mfma_tile(acc, buf, Wf + (size_t)d*128*128, w, q, r);
  }

  if constexpr (!IS_L2){
    #pragma unroll
    for (int mt = 0; mt < 2; mt++)
      #pragma unroll
      for (int n2 = 0; n2 < 2; n2++){
        int col = w*32 + n2*16 + r;
        float bA = biasA[col];
        #pragma unroll
        for (int rr = 0; rr < 4; rr++){
          int row = m0 + mt*16 + q*4 + rr;
          outB[(size_t)row*128 + col] = f2bf(elu1(acc[mt][n2][rr] + bA));
        }
      }
  } else {
    // phase 10: shortcut over sel==0 edges from X, MFMA with W3f.
    // d=8 used agg[0]; shortcut uses agg[1] (last read by mfma(7), which every
    // wave completed before barrier(8)).
    unsigned short* bufS = agg[1];
    {
      int bA = rid*9, bB = (16 + rid)*9;
      int sA = rsl[bA] - lo, eA = rsl[bA+1] - lo;
      int sB = rsl[bB] - lo, eB = rsl[bB+1] - lo;
      f32x4 aA0 = (f32x4){0,0,0,0}, aA1 = (f32x4){0,0,0,0};
      f32x4 aB0 = (f32x4){0,0,0,0}, aB1 = (f32x4){0,0,0,0};
      int lenA = eA - sA, lenB = eB - sB;
      int n = lenA > lenB ? lenA : lenB;
      for (int it = 0; it < n; it++){
        int iA = sA + it, iB = sB + it;
        bool dA = iA < eA, dB = iB < eB;
        int kA = dA ? ((iA < SKEY_CAP) ? skey[iA] : sorted[lo + iA]) : 0;
        int kB = dB ? ((iB < SKEY_CAP) ? skey[iB] : sorted[lo + iB]) : 0;
        short8 vA = *(const short8*)(X + (size_t)kA*128 + c*8);
        short8 vB = *(const short8*)(X + (size_t)kB*128 + c*8);
        if (dA){
          aA0[0] += bf2f((unsigned short)vA[0]); aA0[1] += bf2f((unsigned short)vA[1]);
          aA0[2] += bf2f((unsigned short)vA[2]); aA0[3] += bf2f((unsigned short)vA[3]);
          aA1[0] += bf2f((unsigned short)vA[4]); aA1[1] += bf2f((unsigned short)vA[5]);
          aA1[2] += bf2f((unsigned short)vA[6]); aA1[3] += bf2f((unsigned short)vA[7]);
        }
        if (dB){
          aB0[0] += bf2f((unsigned short)vB[0]); aB0[1] += bf2f((unsigned short)vB[1]);
          aB0[2] += bf2f((unsigned short)vB[2]); aB0[3] += bf2f((unsigned short)vB[3]);
          aB1[0] += bf2f((unsigned short)vB[4]); aB1[1] += bf2f((unsigned short)vB[5]);
          aB1[2] += bf2f((unsigned short)vB[6]); aB1[3] += bf2f((unsigned short)vB[7]);
        }
      }
      short8 oA;
      oA[0]=(short)f2bf(aA0[0]); oA[1]=(short)f2bf(aA0[1]); oA[2]=(short)f2bf(aA0[2]); oA[3]=(short)f2bf(aA0[3]);
      oA[4]=(short)f2bf(aA1[0]); oA[5]=(short)f2bf(aA1[1]); oA[6]=(short)f2bf(aA1[2]); oA[7]=(short)f2bf(aA1[3]);
      *(short8*)&bufS[rid*APITCH + c*8] = oA;
      short8 oB;
      oB[0]=(short)f2bf(aB0[0]); oB[1]=(short)f2bf(aB0[1]); oB[2]=(short)f2bf(aB0[2]); oB[3]=(short)f2bf(aB0[3]);
      oB[4]=(short)f2bf(aB1[0]); oB[5]=(short)f2bf(aB1[1]); oB[6]=(short)f2bf(aB1[2]); oB[7]=(short)f2bf(aB1[3]);
      *(short8*)&bufS[(16 + rid)*APITCH + c*8] = oB;
    }
    __syncthreads();
    f32x4 sca[2][2];
    #pragma unroll
    for (int mt = 0; mt < 2; mt++){ sca[mt][0] = (f32x4){0,0,0,0}; sca[mt][1] = (f32x4){0,0,0,0}; }
    mfma_tile(sca, bufS, W3f, w, q, r);
    #pragma unroll
    for (int mt = 0; mt < 2; mt++)
      #pragma unroll
      for (int n2 = 0; n2 < 2; n2++){
        int col = w*32 + n2*16 + r;
        float bA = biasA[col], b3 = bias3[col], s3 = s3v[col];
        #pragma unroll
        for (int rr = 0; rr < 4; rr++){
          int row = m0 + mt*16 + q*4 + rr;
          float h = elu1(acc[mt][n2][rr] + bA);
          outF[(size_t)row*128 + col] = elu1(h*s3 + sca[mt][n2][rr] + b3);
        }
      }
  }
}

extern "C" void kernel_launch(void* const* d_in, const int* in_sizes, int n_in,
                              void* d_out, int out_size, void* d_ws, size_t ws_size,
                              hipStream_t stream){
  const float* x   = (const float*)d_in[0];
  const int*   ei  = (const int*)d_in[1];
  const int*   sel = (const int*)d_in[2];
  const float* W1  = (const float*)d_in[3];
  const float* b1  = (const float*)d_in[4];
  const float* g1  = (const float*)d_in[5];
  const float* be1 = (const float*)d_in[6];
  const float* rm1 = (const float*)d_in[7];
  const float* rv1 = (const float*)d_in[8];
  const float* W2  = (const float*)d_in[9];
  const float* b2  = (const float*)d_in[10];
  const float* g2  = (const float*)d_in[11];
  const float* be2 = (const float*)d_in[12];
  const float* rm2 = (const float*)d_in[13];
  const float* rv2 = (const float*)d_in[14];
  const float* W3  = (const float*)d_in[15];
  const float* b3  = (const float*)d_in[16];
  const float* g3  = (const float*)d_in[17];
  const float* be3 = (const float*)d_in[18];
  const float* rm3 = (const float*)d_in[19];
  const float* rv3 = (const float*)d_in[20];

  char* ws = (char*)d_ws;
  unsigned short* xb   = (unsigned short*)(ws);                  // 16.78 MB
  unsigned short* h1   = (unsigned short*)(ws + 16777216);       // 16.78 MB
  unsigned short* Wt1  = (unsigned short*)(ws + 33554432);       // 327,680 B (incl. W3fold @ rows 1152+)
  unsigned short* Wt2  = (unsigned short*)(ws + 33882112);       // 294,912 B
  float* bias1  = (float*)(ws + 34177024);
  float* bias2  = bias1 + 128;
  float* bias3  = bias1 + 256;
  float* s3v    = bias1 + 384;
  int* hist     = (int*)(ws + 34179072);                         // NBINS*4 = 2.36 MB
  int* rs       = (int*)(ws + 36538368);                         // (NBINS+1)*4
  int* cursor   = (int*)(ws + 38897920);                         // NBINS*4
  int* bsum     = (int*)(ws + 41257216);                         // 4 KB
  int* bsumx    = (int*)(ws + 41261312);                         // 4 KB
  int* bsumT    = (int*)(ws + 41265408);                         // 16 B
  int* sorted   = (int*)(ws + 41265664);                         // NBINS*4; end ~43.6 MB

  const int* srcp = ei;
  const int* dstp = ei + NEDGE;

  hipMemsetAsync(hist, 0, NBINS*sizeof(int), stream);
  prep_w<<<1216, 256, 0, stream>>>(W1, W2, W3, g1, rv1, g2, rv2, g3, rv3, Wt1, Wt2);
  prep_bias<<<1, 128, 0, stream>>>(b1,g1,be1,rm1,rv1, b2,g2,be2,rm2,rv2, b3,g3,be3,rm3,rv3,
                                   bias1, bias2, bias3, s3v);
  xcast_k<<<4096, 256, 0, stream>>>(x, xb);
  hist_k<<<NEDGE/256, 256, 0, stream>>>(dstp, sel, hist);
  scan1_k<<<NBINS/1024, 256, 0, stream>>>(hist, rs, bsum);       // 576 blocks
  scan1_k<<<1, 256, 0, stream>>>(bsum, bsumx, bsumT);            // scan 576 block sums (tail garbage harmless)
  scan3_k<<<NBINS/256, 256, 0, stream>>>(rs, bsumx, cursor);
  scatter_k<<<NEDGE/256, 256, 0, stream>>>(srcp, dstp, sel, cursor, sorted);

  layer_k<0><<<2048, 256, 0, stream>>>(xb, nullptr, Wt1, nullptr, rs, sorted,
                                       bias1, nullptr, nullptr, h1, nullptr);
  layer_k<1><<<2048, 256, 0, stream>>>(h1, xb, Wt2, Wt1 + 1152*128, rs, sorted,
                                       bias2, bias3, s3v, nullptr, (float*)d_out);
}

// Round 8
// 371.405 us; speedup vs baseline: 1.4140x; 1.0299x over previous
//
#include <hip/hip_runtime.h>
#include <hip/hip_bf16.h>
#include <math.h>

#define N_NODES 65536
#define NDIR 9
#define NEDGE 589824
#define NBINS (N_NODES*NDIR)        // bin = dst*9 + sel (contiguous per node)
#define TILE_M 32
#define SKEY_CAP 1024
#define APITCH 136

typedef __attribute__((ext_vector_type(8))) short short8;
typedef __attribute__((ext_vector_type(4))) float f32x4;

__device__ inline float bf2f(unsigned short u){ return __uint_as_float(((unsigned int)u)<<16); }
__device__ inline unsigned short f2bf(float f){
  unsigned int x = __float_as_uint(f);
  x += 0x7fff + ((x>>16)&1);           // round-to-nearest-even
  return (unsigned short)(x>>16);
}
__device__ inline float elu1(float x){ return x>0.f ? x : expm1f(x); }

__device__ inline void acc8(f32x4& a0, f32x4& a1, short8 v){
  a0[0] += bf2f((unsigned short)v[0]); a0[1] += bf2f((unsigned short)v[1]);
  a0[2] += bf2f((unsigned short)v[2]); a0[3] += bf2f((unsigned short)v[3]);
  a1[0] += bf2f((unsigned short)v[4]); a1[1] += bf2f((unsigned short)v[5]);
  a1[2] += bf2f((unsigned short)v[6]); a1[3] += bf2f((unsigned short)v[7]);
}

// ---- fused prep: zero hist | fold BN into W (bf16, transposed) | biases | cast x ----
// blocks [0,576): zero hist (int4).  [576,1792): prep_w.  1792: biases.  [1793,5889): xcast.
__global__ void prep_all(const float* __restrict__ x, unsigned short* __restrict__ xb,
                         const float* __restrict__ W1, const float* __restrict__ W2,
                         const float* __restrict__ W3,
                         const float* __restrict__ b1, const float* __restrict__ g1,
                         const float* __restrict__ be1, const float* __restrict__ rm1,
                         const float* __restrict__ rv1,
                         const float* __restrict__ b2, const float* __restrict__ g2,
                         const float* __restrict__ be2, const float* __restrict__ rm2,
                         const float* __restrict__ rv2,
                         const float* __restrict__ b3, const float* __restrict__ g3,
                         const float* __restrict__ be3, const float* __restrict__ rm3,
                         const float* __restrict__ rv3,
                         unsigned short* __restrict__ Wt1, unsigned short* __restrict__ Wt2,
                         float* __restrict__ bias1, float* __restrict__ bias2,
                         float* __restrict__ bias3, float* __restrict__ s3v,
                         int* __restrict__ hist){
  const float eps = 1e-5f;
  int b = blockIdx.x, tid = threadIdx.x;
  if (b < 576){
    int4 z = {0,0,0,0};
    *(int4*)&hist[(b*256 + tid)*4] = z;
  } else if (b < 1792){
    int idx = (b - 576)*256 + tid;
    if (idx < 1280*128) {
      int n = idx >> 7, k = idx & 127;
      float v;
      if (n < 1152) { int d = n >> 7, c = n & 127;
        float s = g1[c]*rsqrtf(rv1[c]+eps); v = W1[(d*128 + k)*128 + c] * s; }
      else { int c = n - 1152;
        float s = g3[c]*rsqrtf(rv3[c]+eps); v = W3[k*128 + c] * s; }
      Wt1[idx] = f2bf(v);
    } else {
      int j = idx - 1280*128;
      int n = j >> 7, k = j & 127;
      int d = n >> 7, c = n & 127;
      float s = g2[c]*rsqrtf(rv2[c]+eps);
      Wt2[j] = f2bf(W2[(d*128 + k)*128 + c] * s);
    }
  } else if (b == 1792){
    if (tid < 128){
      int c = tid;
      float s1 = g1[c]*rsqrtf(rv1[c]+eps);
      bias1[c] = (b1[c]-rm1[c])*s1 + be1[c];
      float s2 = g2[c]*rsqrtf(rv2[c]+eps);
      bias2[c] = (b2[c]-rm2[c])*s2 + be2[c];
      float s3 = g3[c]*rsqrtf(rv3[c]+eps);
      bias3[c] = (b3[c]-rm3[c])*s3 + be3[c];
      s3v[c] = s3;
    }
  } else {
    int i = ((b - 1793)*256 + tid)*8;
    f32x4 f0 = *(const f32x4*)(x + i);
    f32x4 f1 = *(const f32x4*)(x + i + 4);
    short8 t;
    #pragma unroll
    for (int j = 0; j < 4; j++){ t[j] = (short)f2bf(f0[j]); t[4+j] = (short)f2bf(f1[j]); }
    *(short8*)(xb + i) = t;
  }
}

// ---- CSR build over (dst,sel) bins, bin = dst*9+sel ----
__global__ void hist_k(const int* __restrict__ dst, const int* __restrict__ sel,
                       int* __restrict__ hist){
  int e = blockIdx.x*256 + threadIdx.x;
  atomicAdd(&hist[dst[e]*9 + sel[e]], 1);
}

// exclusive scan of 1024 ints per block; block total -> bsum[blockIdx]
__global__ void scan1_k(const int* __restrict__ in, int* __restrict__ out, int* __restrict__ bsum){
  __shared__ int wsum[4];
  int t = threadIdx.x;
  int base = blockIdx.x*1024 + t*4;
  int4 v = *(const int4*)(in + base);
  int s = v.x + v.y + v.z + v.w;
  int lane = t & 63, w = t >> 6;
  int inc = s;
  #pragma unroll
  for (int o = 1; o < 64; o <<= 1){ int n = __shfl_up(inc, o); if (lane >= o) inc += n; }
  if (lane == 63) wsum[w] = inc;
  __syncthreads();
  int acc = 0;
  for (int i = 0; i < w; i++) acc += wsum[i];
  int ex = acc + inc - s;
  out[base] = ex; out[base+1] = ex + v.x; out[base+2] = ex + v.x + v.y; out[base+3] = ex + v.x + v.y + v.z;
  if (t == 255) bsum[blockIdx.x] = acc + inc;
}

__global__ void scan3_k(int* __restrict__ rs, const int* __restrict__ bsumx, int* __restrict__ cursor){
  int i = blockIdx.x*256 + threadIdx.x;
  int v = rs[i] + bsumx[i >> 10];
  rs[i] = v; cursor[i] = v;
  if (i == 0) rs[NBINS] = NEDGE;        // sentinel: end(bin b) == rs[b+1]
}

__global__ void scatter_k(const int* __restrict__ src, const int* __restrict__ dst,
                          const int* __restrict__ sel,
                          int* __restrict__ cursor, int* __restrict__ sorted){
  int e = blockIdx.x*256 + threadIdx.x;
  int bin = dst[e]*9 + sel[e];
  int pos = atomicAdd(&cursor[bin], 1);
  sorted[pos] = src[e];
}

// ---- MFMA: wave computes all 32 rows x 32 cols (cols [w*32,w*32+32)) ----
__device__ __forceinline__ void mfma_tile(f32x4 acc[2][2],
                                          const unsigned short* agg,
                                          const unsigned short* __restrict__ Wd,
                                          int w, int q, int r){
  #pragma unroll
  for (int kk = 0; kk < 4; kk++){
    const unsigned short* wp = Wd + (size_t)(w*32 + r)*128 + kk*32 + q*8;
    short8 b0 = *(const short8*)wp;
    short8 b1 = *(const short8*)(wp + 16*128);
    #pragma unroll
    for (int mt = 0; mt < 2; mt++){
      short8 av = *(const short8*)&agg[(mt*16 + r)*APITCH + kk*32 + q*8];
      acc[mt][0] = __builtin_amdgcn_mfma_f32_16x16x32_bf16(av, b0, acc[mt][0], 0, 0, 0);
      acc[mt][1] = __builtin_amdgcn_mfma_f32_16x16x32_bf16(av, b1, acc[mt][1], 0, 0, 0);
    }
  }
}

// ---- fused layer v7: v1 structure (measured best, 107.7us) + cross-phase prefetch:
// first edge of each of this thread's two rows for dir d+1 is loaded into registers
// BEFORE the mfma(d)+barrier phase, hiding its latency under compute (T14).
template<int IS_L2>
__global__ __launch_bounds__(256, 8) void layer_k(
    const unsigned short* __restrict__ H,     // layer input activations [N][128] bf16
    const unsigned short* __restrict__ X,     // xb (shortcut input, L2 only)
    const unsigned short* __restrict__ Wf,    // [1152][128] folded dir weights
    const unsigned short* __restrict__ W3f,   // [128][128] folded shortcut weights (L2)
    const int* __restrict__ rs, const int* __restrict__ sorted,
    const float* __restrict__ biasA, const float* __restrict__ bias3,
    const float* __restrict__ s3v,
    unsigned short* __restrict__ outB, float* __restrict__ outF){
  __shared__ __align__(16) unsigned short agg[TILE_M*APITCH];   // 8.7 KB
  __shared__ int skey[SKEY_CAP];                                 // 4 KB block edge keys
  __shared__ int rsl[TILE_M*9 + 1];                              // block bin offsets
  const int tid = threadIdx.x;
  const int w = tid >> 6, lane = tid & 63;
  const int q = lane >> 4, r = lane & 15;
  const int rid = tid >> 4, c = tid & 15;                        // 16 lanes per row, chunk c
  const int m0 = blockIdx.x * TILE_M;

  for (int i = tid; i <= TILE_M*9; i += 256) rsl[i] = rs[m0*9 + i];
  __syncthreads();
  const int lo = rsl[0];
  const int cnt = rsl[TILE_M*9] - lo;

  // prefetch first edges of dir-0 bins (keys from global sorted; skey not yet staged)
  short8 pvA, pvB;
  {
    int aA = rsl[rid*9];            // absolute start of bin (rid, 0)
    int aB = rsl[(16+rid)*9];
    if (aA > NEDGE-1) aA = NEDGE-1;
    if (aB > NEDGE-1) aB = NEDGE-1;
    pvA = *(const short8*)(H + (size_t)sorted[aA]*128 + c*8);
    pvB = *(const short8*)(H + (size_t)sorted[aB]*128 + c*8);
  }

  for (int i = tid; i < cnt && i < SKEY_CAP; i += 256) skey[i] = sorted[lo + i];

  f32x4 acc[2][2];
  #pragma unroll
  for (int mt = 0; mt < 2; mt++){ acc[mt][0] = (f32x4){0,0,0,0}; acc[mt][1] = (f32x4){0,0,0,0}; }

  #pragma unroll 1
  for (int d = 0; d < 9; d++){
    __syncthreads();                     // skey ready (d=0) / agg consumed (d>0)
    // stream A: row rid
    {
      int b = rid*9 + d;
      int s = rsl[b] - lo, e = rsl[b+1] - lo;
      f32x4 a0 = {0,0,0,0}, a1 = {0,0,0,0};
      if (e > s){
        acc8(a0, a1, pvA);
        for (int i = s+1; i < e; i++){
          int key = (i < SKEY_CAP) ? skey[i] : sorted[lo + i];
          short8 v = *(const short8*)(H + (size_t)key*128 + c*8);
          acc8(a0, a1, v);
        }
      }
      short8 o;
      o[0]=(short)f2bf(a0[0]); o[1]=(short)f2bf(a0[1]); o[2]=(short)f2bf(a0[2]); o[3]=(short)f2bf(a0[3]);
      o[4]=(short)f2bf(a1[0]); o[5]=(short)f2bf(a1[1]); o[6]=(short)f2bf(a1[2]); o[7]=(short)f2bf(a1[3]);
      *(short8*)&agg[rid*APITCH + c*8] = o;
    }
    // stream B: row rid+16
    {
      int b = (16 + rid)*9 + d;
      int s = rsl[b] - lo, e = rsl[b+1] - lo;
      f32x4 a0 = {0,0,0,0}, a1 = {0,0,0,0};
      if (e > s){
        acc8(a0, a1, pvB);
        for (int i = s+1; i < e; i++){
          int key = (i < SKEY_CAP) ? skey[i] : sorted[lo + i];
          short8 v = *(const short8*)(H + (size_t)key*128 + c*8);
          acc8(a0, a1, v);
        }
      }
      short8 o;
      o[0]=(short)f2bf(a0[0]); o[1]=(short)f2bf(a0[1]); o[2]=(short)f2bf(a0[2]); o[3]=(short)f2bf(a0[3]);
      o[4]=(short)f2bf(a1[0]); o[5]=(short)f2bf(a1[1]); o[6]=(short)f2bf(a1[2]); o[7]=(short)f2bf(a1[3]);
      *(short8*)&agg[(16 + rid)*APITCH + c*8] = o;
    }
    // prefetch first edges for next phase (dir d+1, or shortcut sel-0 from X)
    if (d < 8){
      int aA = rsl[rid*9 + d + 1];
      int aB = rsl[(16+rid)*9 + d + 1];
      if (aA > NEDGE-1) aA = NEDGE-1;
      if (aB > NEDGE-1) aB = NEDGE-1;
      pvA = *(const short8*)(H + (size_t)sorted[aA]*128 + c*8);
      pvB = *(const short8*)(H + (size_t)sorted[aB]*128 + c*8);
    } else if (IS_L2){
      int aA = rsl[rid*9];
      int aB = rsl[(16+rid)*9];
      if (aA > NEDGE-1) aA = NEDGE-1;
      if (aB > NEDGE-1) aB = NEDGE-1;
      pvA = *(const short8*)(X + (size_t)sorted[aA]*128 + c*8);
      pvB = *(const short8*)(X + (size_t)sorted[aB]*128 + c*8);
    }
    __syncthreads();
    mfma_tile(acc, agg, Wf + (size_t)d*128*128, w, q, r);
  }

  if constexpr (!IS_L2){
    #pragma unroll
    for (int mt = 0; mt < 2; mt++)
      #pragma unroll
      for (int n2 = 0; n2 < 2; n2++){
        int col = w*32 + n2*16 + r;
        float bA = biasA[col];
        #pragma unroll
        for (int rr = 0; rr < 4; rr++){
          int row = m0 + mt*16 + q*4 + rr;
          outB[(size_t)row*128 + col] = f2bf(elu1(acc[mt][n2][rr] + bA));
        }
      }
  } else {
    // 10th phase: shortcut gather over sel==0 edges from X, MFMA with W3f
    __syncthreads();                     // agg consumed by last mfma
    {
      int b = rid*9;
      int s = rsl[b] - lo, e = rsl[b+1] - lo;
      f32x4 a0 = {0,0,0,0}, a1 = {0,0,0,0};
      if (e > s){
        acc8(a0, a1, pvA);
        for (int i = s+1; i < e; i++){
          int key = (i < SKEY_CAP) ? skey[i] : sorted[lo + i];
          short8 v = *(const short8*)(X + (size_t)key*128 + c*8);
          acc8(a0, a1, v);
        }
      }
      short8 o;
      o[0]=(short)f2bf(a0[0]); o[1]=(short)f2bf(a0[1]); o[2]=(short)f2bf(a0[2]); o[3]=(short)f2bf(a0[3]);
      o[4]=(short)f2bf(a1[0]); o[5]=(short)f2bf(a1[1]); o[6]=(short)f2bf(a1[2]); o[7]=(short)f2bf(a1[3]);
      *(short8*)&agg[rid*APITCH + c*8] = o;
    }
    {
      int b = (16 + rid)*9;
      int s = rsl[b] - lo, e = rsl[b+1] - lo;
      f32x4 a0 = {0,0,0,0}, a1 = {0,0,0,0};
      if (e > s){
        acc8(a0, a1, pvB);
        for (int i = s+1; i < e; i++){
          int key = (i < SKEY_CAP) ? skey[i] : sorted[lo + i];
          short8 v = *(const short8*)(X + (size_t)key*128 + c*8);
          acc8(a0, a1, v);
        }
      }
      short8 o;
      o[0]=(short)f2bf(a0[0]); o[1]=(short)f2bf(a0[1]); o[2]=(short)f2bf(a0[2]); o[3]=(short)f2bf(a0[3]);
      o[4]=(short)f2bf(a1[0]); o[5]=(short)f2bf(a1[1]); o[6]=(short)f2bf(a1[2]); o[7]=(short)f2bf(a1[3]);
      *(short8*)&agg[(16 + rid)*APITCH + c*8] = o;
    }
    __syncthreads();
    f32x4 sca[2][2];
    #pragma unroll
    for (int mt = 0; mt < 2; mt++){ sca[mt][0] = (f32x4){0,0,0,0}; sca[mt][1] = (f32x4){0,0,0,0}; }
    mfma_tile(sca, agg, W3f, w, q, r);
    #pragma unroll
    for (int mt = 0; mt < 2; mt++)
      #pragma unroll
      for (int n2 = 0; n2 < 2; n2++){
        int col = w*32 + n2*16 + r;
        float bA = biasA[col], b3 = bias3[col], s3 = s3v[col];
        #pragma unroll
        for (int rr = 0; rr < 4; rr++){
          int row = m0 + mt*16 + q*4 + rr;
          float h = elu1(acc[mt][n2][rr] + bA);
          outF[(size_t)row*128 + col] = elu1(h*s3 + sca[mt][n2][rr] + b3);
        }
      }
  }
}

extern "C" void kernel_launch(void* const* d_in, const int* in_sizes, int n_in,
                              void* d_out, int out_size, void* d_ws, size_t ws_size,
                              hipStream_t stream){
  const float* x   = (const float*)d_in[0];
  const int*   ei  = (const int*)d_in[1];
  const int*   sel = (const int*)d_in[2];
  const float* W1  = (const float*)d_in[3];
  const float* b1  = (const float*)d_in[4];
  const float* g1  = (const float*)d_in[5];
  const float* be1 = (const float*)d_in[6];
  const float* rm1 = (const float*)d_in[7];
  const float* rv1 = (const float*)d_in[8];
  const float* W2  = (const float*)d_in[9];
  const float* b2  = (const float*)d_in[10];
  const float* g2  = (const float*)d_in[11];
  const float* be2 = (const float*)d_in[12];
  const float* rm2 = (const float*)d_in[13];
  const float* rv2 = (const float*)d_in[14];
  const float* W3  = (const float*)d_in[15];
  const float* b3  = (const float*)d_in[16];
  const float* g3  = (const float*)d_in[17];
  const float* be3 = (const float*)d_in[18];
  const float* rm3 = (const float*)d_in[19];
  const float* rv3 = (const float*)d_in[20];

  char* ws = (char*)d_ws;
  unsigned short* xb   = (unsigned short*)(ws);                  // 16.78 MB
  unsigned short* h1   = (unsigned short*)(ws + 16777216);       // 16.78 MB
  unsigned short* Wt1  = (unsigned short*)(ws + 33554432);       // 327,680 B (incl. W3fold @ rows 1152+)
  unsigned short* Wt2  = (unsigned short*)(ws + 33882112);       // 294,912 B
  float* bias1  = (float*)(ws + 34177024);
  float* bias2  = bias1 + 128;
  float* bias3  = bias1 + 256;
  float* s3v    = bias1 + 384;
  int* hist     = (int*)(ws + 34179072);                         // NBINS*4 = 2.36 MB
  int* rs       = (int*)(ws + 36538368);                         // (NBINS+1)*4
  int* cursor   = (int*)(ws + 38897920);                         // NBINS*4
  int* bsum     = (int*)(ws + 41257216);                         // 4 KB
  int* bsumx    = (int*)(ws + 41261312);                         // 4 KB
  int* bsumT    = (int*)(ws + 41265408);                         // 16 B
  int* sorted   = (int*)(ws + 41265664);                         // NBINS*4; end ~43.6 MB

  const int* srcp = ei;
  const int* dstp = ei + NEDGE;

  prep_all<<<5889, 256, 0, stream>>>(x, xb, W1, W2, W3,
                                     b1, g1, be1, rm1, rv1,
                                     b2, g2, be2, rm2, rv2,
                                     b3, g3, be3, rm3, rv3,
                                     Wt1, Wt2, bias1, bias2, bias3, s3v, hist);
  hist_k<<<NEDGE/256, 256, 0, stream>>>(dstp, sel, hist);
  scan1_k<<<NBINS/1024, 256, 0, stream>>>(hist, rs, bsum);       // 576 blocks
  scan1_k<<<1, 256, 0, stream>>>(bsum, bsumx, bsumT);            // scan 576 block sums (tail garbage harmless)
  scan3_k<<<NBINS/256, 256, 0, stream>>>(rs, bsumx, cursor);
  scatter_k<<<NEDGE/256, 256, 0, stream>>>(srcp, dstp, sel, cursor, sorted);

  layer_k<0><<<2048, 256, 0, stream>>>(xb, nullptr, Wt1, nullptr, rs, sorted,
                                       bias1, nullptr, nullptr, h1, nullptr);
  layer_k<1><<<2048, 256, 0, stream>>>(h1, xb, Wt2, Wt1 + 1152*128, rs, sorted,
                                       bias2, bias3, s3v, nullptr, (float*)d_out);
}

// Round 9
// 364.042 us; speedup vs baseline: 1.4426x; 1.0202x over previous
//
#include <hip/hip_runtime.h>
#include <hip/hip_bf16.h>
#include <math.h>

#define N_NODES 65536
#define NDIR 9
#define NEDGE 589824
#define TILE_M 32
#define CAP 512                     // per-block staged-edge capacity (Poisson(288)+13sigma)
#define APITCH 136

typedef __attribute__((ext_vector_type(8))) short short8;
typedef __attribute__((ext_vector_type(4))) float f32x4;

__device__ inline float bf2f(unsigned short u){ return __uint_as_float(((unsigned int)u)<<16); }
__device__ inline unsigned short f2bf(float f){
  unsigned int x = __float_as_uint(f);
  x += 0x7fff + ((x>>16)&1);           // round-to-nearest-even
  return (unsigned short)(x>>16);
}
__device__ inline float elu1(float x){ return x>0.f ? x : expm1f(x); }

__device__ inline void acc8(f32x4& a0, f32x4& a1, short8 v){
  a0[0] += bf2f((unsigned short)v[0]); a0[1] += bf2f((unsigned short)v[1]);
  a0[2] += bf2f((unsigned short)v[2]); a0[3] += bf2f((unsigned short)v[3]);
  a1[0] += bf2f((unsigned short)v[4]); a1[1] += bf2f((unsigned short)v[5]);
  a1[2] += bf2f((unsigned short)v[6]); a1[3] += bf2f((unsigned short)v[7]);
}

// ---- fused prep: zero hist | fold BN into W (bf16, transposed) | biases | cast x ----
// blocks [0,64): zero hist (64K ints). [64,1280): prep_w. 1280: biases. [1281,5377): xcast.
__global__ void prep_all(const float* __restrict__ x, unsigned short* __restrict__ xb,
                         const float* __restrict__ W1, const float* __restrict__ W2,
                         const float* __restrict__ W3,
                         const float* __restrict__ b1, const float* __restrict__ g1,
                         const float* __restrict__ be1, const float* __restrict__ rm1,
                         const float* __restrict__ rv1,
                         const float* __restrict__ b2, const float* __restrict__ g2,
                         const float* __restrict__ be2, const float* __restrict__ rm2,
                         const float* __restrict__ rv2,
                         const float* __restrict__ b3, const float* __restrict__ g3,
                         const float* __restrict__ be3, const float* __restrict__ rm3,
                         const float* __restrict__ rv3,
                         unsigned short* __restrict__ Wt1, unsigned short* __restrict__ Wt2,
                         float* __restrict__ bias1, float* __restrict__ bias2,
                         float* __restrict__ bias3, float* __restrict__ s3v,
                         int* __restrict__ hist){
  const float eps = 1e-5f;
  int b = blockIdx.x, tid = threadIdx.x;
  if (b < 64){
    int4 z = {0,0,0,0};
    *(int4*)&hist[(b*256 + tid)*4] = z;
  } else if (b < 1280){
    int idx = (b - 64)*256 + tid;
    if (idx < 1280*128) {
      int n = idx >> 7, k = idx & 127;
      float v;
      if (n < 1152) { int d = n >> 7, c = n & 127;
        float s = g1[c]*rsqrtf(rv1[c]+eps); v = W1[(d*128 + k)*128 + c] * s; }
      else { int c = n - 1152;
        float s = g3[c]*rsqrtf(rv3[c]+eps); v = W3[k*128 + c] * s; }
      Wt1[idx] = f2bf(v);
    } else {
      int j = idx - 1280*128;
      int n = j >> 7, k = j & 127;
      int d = n >> 7, c = n & 127;
      float s = g2[c]*rsqrtf(rv2[c]+eps);
      Wt2[j] = f2bf(W2[(d*128 + k)*128 + c] * s);
    }
  } else if (b == 1280){
    if (tid < 128){
      int c = tid;
      float s1 = g1[c]*rsqrtf(rv1[c]+eps);
      bias1[c] = (b1[c]-rm1[c])*s1 + be1[c];
      float s2 = g2[c]*rsqrtf(rv2[c]+eps);
      bias2[c] = (b2[c]-rm2[c])*s2 + be2[c];
      float s3 = g3[c]*rsqrtf(rv3[c]+eps);
      bias3[c] = (b3[c]-rm3[c])*s3 + be3[c];
      s3v[c] = s3;
    }
  } else {
    int i = ((b - 1281)*256 + tid)*8;
    f32x4 f0 = *(const f32x4*)(x + i);
    f32x4 f1 = *(const f32x4*)(x + i + 4);
    short8 t;
    #pragma unroll
    for (int j = 0; j < 4; j++){ t[j] = (short)f2bf(f0[j]); t[4+j] = (short)f2bf(f1[j]); }
    *(short8*)(xb + i) = t;
  }
}

// ---- per-NODE CSR (65536 bins; sel refined inside layer) ----
__global__ void hist_k(const int* __restrict__ dst, int* __restrict__ hist){
  int e = blockIdx.x*256 + threadIdx.x;
  atomicAdd(&hist[dst[e]], 1);
}

// exclusive scan of 1024 ints per block; block total -> bsum[blockIdx]
__global__ void scan1_k(const int* __restrict__ in, int* __restrict__ out, int* __restrict__ bsum){
  __shared__ int wsum[4];
  int t = threadIdx.x;
  int base = blockIdx.x*1024 + t*4;
  int4 v = *(const int4*)(in + base);
  int s = v.x + v.y + v.z + v.w;
  int lane = t & 63, w = t >> 6;
  int inc = s;
  #pragma unroll
  for (int o = 1; o < 64; o <<= 1){ int n = __shfl_up(inc, o); if (lane >= o) inc += n; }
  if (lane == 63) wsum[w] = inc;
  __syncthreads();
  int acc = 0;
  for (int i = 0; i < w; i++) acc += wsum[i];
  int ex = acc + inc - s;
  out[base] = ex; out[base+1] = ex + v.x; out[base+2] = ex + v.x + v.y; out[base+3] = ex + v.x + v.y + v.z;
  if (t == 255) bsum[blockIdx.x] = acc + inc;
}

__global__ void scan3_k(int* __restrict__ rs, const int* __restrict__ bsumx, int* __restrict__ cursor){
  int i = blockIdx.x*256 + threadIdx.x;
  int v = rs[i] + bsumx[i >> 10];
  rs[i] = v; cursor[i] = v;
  if (i == 0) rs[N_NODES] = NEDGE;      // sentinel
}

// scatter packed key: src | sel<<16  (src < 65536 fits 16 bits)
__global__ void scatter_k(const int* __restrict__ src, const int* __restrict__ dst,
                          const int* __restrict__ sel,
                          int* __restrict__ cursor, int* __restrict__ sorted){
  int e = blockIdx.x*256 + threadIdx.x;
  int pos = atomicAdd(&cursor[dst[e]], 1);
  sorted[pos] = src[e] | (sel[e] << 16);
}

// ---- MFMA: wave computes all 32 rows x 32 cols (cols [w*32,w*32+32)) ----
__device__ __forceinline__ void mfma_tile(f32x4 acc[2][2],
                                          const unsigned short* agg,
                                          const unsigned short* __restrict__ Wd,
                                          int w, int q, int r){
  #pragma unroll
  for (int kk = 0; kk < 4; kk++){
    const unsigned short* wp = Wd + (size_t)(w*32 + r)*128 + kk*32 + q*8;
    short8 b0 = *(const short8*)wp;
    short8 b1 = *(const short8*)(wp + 16*128);
    #pragma unroll
    for (int mt = 0; mt < 2; mt++){
      short8 av = *(const short8*)&agg[(mt*16 + r)*APITCH + kk*32 + q*8];
      acc[mt][0] = __builtin_amdgcn_mfma_f32_16x16x32_bf16(av, b0, acc[mt][0], 0, 0, 0);
      acc[mt][1] = __builtin_amdgcn_mfma_f32_16x16x32_bf16(av, b1, acc[mt][1], 0, 0, 0);
    }
  }
}

// ---- fused layer v8: v1 gather/MFMA core (measured best) + in-LDS counting sort
// of this block's packed (src,sel) edges into per-(row,dir) bins (replaces the
// global (dst,sel)-bin CSR; global CSR is per-node only).
template<int IS_L2>
__global__ __launch_bounds__(256, 8) void layer_k(
    const unsigned short* __restrict__ H,     // layer input activations [N][128] bf16
    const unsigned short* __restrict__ X,     // xb (shortcut input, L2 only)
    const unsigned short* __restrict__ Wf,    // [1152][128] folded dir weights
    const unsigned short* __restrict__ W3f,   // [128][128] folded shortcut weights (L2)
    const int* __restrict__ rs, const int* __restrict__ sorted,
    const float* __restrict__ biasA, const float* __restrict__ bias3,
    const float* __restrict__ s3v,
    unsigned short* __restrict__ outB, float* __restrict__ outF){
  __shared__ __align__(16) unsigned short agg[TILE_M*APITCH];    // 8704 B
  __shared__ int skey[CAP];                                      // 2048 B packed keys
  __shared__ unsigned short skey2[CAP];                          // 1024 B sorted src
  __shared__ int rsl2[TILE_M + 1];                               // node offsets
  __shared__ int po[TILE_M*9];                                   // local bin starts
  __shared__ int wo[TILE_M*9];                                   // counts -> cursors -> ends
  const int tid = threadIdx.x;
  const int w = tid >> 6, lane = tid & 63;
  const int q = lane >> 4, r = lane & 15;
  const int rid = tid >> 4, c = tid & 15;                        // 16 lanes/row, chunk c
  const int m0 = blockIdx.x * TILE_M;

  if (tid <= TILE_M) rsl2[tid] = rs[m0 + tid];
  for (int i = tid; i < TILE_M*9; i += 256) wo[i] = 0;
  __syncthreads();
  const int lo = rsl2[0];
  const int cnt = rsl2[TILE_M] - lo;
  for (int i = tid; i < cnt && i < CAP; i += 256) skey[i] = sorted[lo + i];
  __syncthreads();

  // count per (node,dir): 8 threads per node walk its staged edges
  {
    const int nl8 = tid >> 3, sub = tid & 7;
    int s = rsl2[nl8] - lo, e = rsl2[nl8+1] - lo;
    if (e > CAP) e = CAP;
    for (int i = s + sub; i < e; i += 8)
      atomicAdd(&wo[nl8*9 + (skey[i] >> 16)], 1);
  }
  __syncthreads();
  // per-node prefix: po = bin start, wo = scatter cursor (becomes end after scatter)
  if (tid < TILE_M){
    int base = rsl2[tid] - lo;
    if (base > CAP) base = CAP;
    #pragma unroll
    for (int d = 0; d < 9; d++){
      int b = tid*9 + d;
      po[b] = base;
      int cc = wo[b];
      wo[b] = base;
      base += cc;
    }
  }
  __syncthreads();
  // scatter staged keys into per-(node,dir) bins (16-bit src)
  {
    const int nl8 = tid >> 3, sub = tid & 7;
    int s = rsl2[nl8] - lo, e = rsl2[nl8+1] - lo;
    if (e > CAP) e = CAP;
    for (int i = s + sub; i < e; i += 8){
      int k = skey[i];
      int pos = atomicAdd(&wo[nl8*9 + (k >> 16)], 1);
      skey2[pos] = (unsigned short)k;
    }
  }
  __syncthreads();

  f32x4 acc[2][2];
  #pragma unroll
  for (int mt = 0; mt < 2; mt++){ acc[mt][0] = (f32x4){0,0,0,0}; acc[mt][1] = (f32x4){0,0,0,0}; }

  #pragma unroll 1
  for (int d = 0; d < 9; d++){
    if (d) __syncthreads();              // agg consumed by previous mfma
    // stream A: row rid
    {
      int b = rid*9 + d;
      int s = po[b], e = wo[b];
      f32x4 a0 = {0,0,0,0}, a1 = {0,0,0,0};
      for (int i = s; i < e; i++){
        int key = skey2[i];
        short8 v = *(const short8*)(H + (size_t)key*128 + c*8);
        acc8(a0, a1, v);
      }
      // tail fallback (only if this node's edges overflowed CAP)
      int ts = rsl2[rid] - lo; if (ts < CAP) ts = CAP;
      int te = rsl2[rid+1] - lo;
      for (int i = ts; i < te; i++){
        int k = sorted[lo + i];
        if ((k >> 16) == d){
          short8 v = *(const short8*)(H + (size_t)(k & 0xFFFF)*128 + c*8);
          acc8(a0, a1, v);
        }
      }
      short8 o;
      o[0]=(short)f2bf(a0[0]); o[1]=(short)f2bf(a0[1]); o[2]=(short)f2bf(a0[2]); o[3]=(short)f2bf(a0[3]);
      o[4]=(short)f2bf(a1[0]); o[5]=(short)f2bf(a1[1]); o[6]=(short)f2bf(a1[2]); o[7]=(short)f2bf(a1[3]);
      *(short8*)&agg[rid*APITCH + c*8] = o;
    }
    // stream B: row rid+16
    {
      int b = (16 + rid)*9 + d;
      int s = po[b], e = wo[b];
      f32x4 a0 = {0,0,0,0}, a1 = {0,0,0,0};
      for (int i = s; i < e; i++){
        int key = skey2[i];
        short8 v = *(const short8*)(H + (size_t)key*128 + c*8);
        acc8(a0, a1, v);
      }
      int ts = rsl2[16+rid] - lo; if (ts < CAP) ts = CAP;
      int te = rsl2[16+rid+1] - lo;
      for (int i = ts; i < te; i++){
        int k = sorted[lo + i];
        if ((k >> 16) == d){
          short8 v = *(const short8*)(H + (size_t)(k & 0xFFFF)*128 + c*8);
          acc8(a0, a1, v);
        }
      }
      short8 o;
      o[0]=(short)f2bf(a0[0]); o[1]=(short)f2bf(a0[1]); o[2]=(short)f2bf(a0[2]); o[3]=(short)f2bf(a0[3]);
      o[4]=(short)f2bf(a1[0]); o[5]=(short)f2bf(a1[1]); o[6]=(short)f2bf(a1[2]); o[7]=(short)f2bf(a1[3]);
      *(short8*)&agg[(16 + rid)*APITCH + c*8] = o;
    }
    __syncthreads();
    mfma_tile(acc, agg, Wf + (size_t)d*128*128, w, q, r);
  }

  if constexpr (!IS_L2){
    #pragma unroll
    for (int mt = 0; mt < 2; mt++)
      #pragma unroll
      for (int n2 = 0; n2 < 2; n2++){
        int col = w*32 + n2*16 + r;
        float bA = biasA[col];
        #pragma unroll
        for (int rr = 0; rr < 4; rr++){
          int row = m0 + mt*16 + q*4 + rr;
          outB[(size_t)row*128 + col] = f2bf(elu1(acc[mt][n2][rr] + bA));
        }
      }
  } else {
    // 10th phase: shortcut over dir-0 bins from X, MFMA with W3f
    __syncthreads();                     // agg consumed by last mfma
    #pragma unroll
    for (int t2 = 0; t2 < 2; t2++){
      int nl = t2*16 + rid;
      int b = nl*9;
      int s = po[b], e = wo[b];
      f32x4 a0 = {0,0,0,0}, a1 = {0,0,0,0};
      for (int i = s; i < e; i++){
        int key = skey2[i];
        short8 v = *(const short8*)(X + (size_t)key*128 + c*8);
        acc8(a0, a1, v);
      }
      int ts = rsl2[nl] - lo; if (ts < CAP) ts = CAP;
      int te = rsl2[nl+1] - lo;
      for (int i = ts; i < te; i++){
        int k = sorted[lo + i];
        if ((k >> 16) == 0){
          short8 v = *(const short8*)(X + (size_t)(k & 0xFFFF)*128 + c*8);
          acc8(a0, a1, v);
        }
      }
      short8 o;
      o[0]=(short)f2bf(a0[0]); o[1]=(short)f2bf(a0[1]); o[2]=(short)f2bf(a0[2]); o[3]=(short)f2bf(a0[3]);
      o[4]=(short)f2bf(a1[0]); o[5]=(short)f2bf(a1[1]); o[6]=(short)f2bf(a1[2]); o[7]=(short)f2bf(a1[3]);
      *(short8*)&agg[nl*APITCH + c*8] = o;
    }
    __syncthreads();
    f32x4 sca[2][2];
    #pragma unroll
    for (int mt = 0; mt < 2; mt++){ sca[mt][0] = (f32x4){0,0,0,0}; sca[mt][1] = (f32x4){0,0,0,0}; }
    mfma_tile(sca, agg, W3f, w, q, r);
    #pragma unroll
    for (int mt = 0; mt < 2; mt++)
      #pragma unroll
      for (int n2 = 0; n2 < 2; n2++){
        int col = w*32 + n2*16 + r;
        float bA = biasA[col], b3 = bias3[col], s3 = s3v[col];
        #pragma unroll
        for (int rr = 0; rr < 4; rr++){
          int row = m0 + mt*16 + q*4 + rr;
          float h = elu1(acc[mt][n2][rr] + bA);
          outF[(size_t)row*128 + col] = elu1(h*s3 + sca[mt][n2][rr] + b3);
        }
      }
  }
}

extern "C" void kernel_launch(void* const* d_in, const int* in_sizes, int n_in,
                              void* d_out, int out_size, void* d_ws, size_t ws_size,
                              hipStream_t stream){
  const float* x   = (const float*)d_in[0];
  const int*   ei  = (const int*)d_in[1];
  const int*   sel = (const int*)d_in[2];
  const float* W1  = (const float*)d_in[3];
  const float* b1  = (const float*)d_in[4];
  const float* g1  = (const float*)d_in[5];
  const float* be1 = (const float*)d_in[6];
  const float* rm1 = (const float*)d_in[7];
  const float* rv1 = (const float*)d_in[8];
  const float* W2  = (const float*)d_in[9];
  const float* b2  = (const float*)d_in[10];
  const float* g2  = (const float*)d_in[11];
  const float* be2 = (const float*)d_in[12];
  const float* rm2 = (const float*)d_in[13];
  const float* rv2 = (const float*)d_in[14];
  const float* W3  = (const float*)d_in[15];
  const float* b3  = (const float*)d_in[16];
  const float* g3  = (const float*)d_in[17];
  const float* be3 = (const float*)d_in[18];
  const float* rm3 = (const float*)d_in[19];
  const float* rv3 = (const float*)d_in[20];

  char* ws = (char*)d_ws;
  unsigned short* xb   = (unsigned short*)(ws);                  // 16.78 MB
  unsigned short* h1   = (unsigned short*)(ws + 16777216);       // 16.78 MB
  unsigned short* Wt1  = (unsigned short*)(ws + 33554432);       // 327,680 B
  unsigned short* Wt2  = (unsigned short*)(ws + 33882112);       // 294,912 B
  float* bias1  = (float*)(ws + 34177024);
  float* bias2  = bias1 + 128;
  float* bias3  = bias1 + 256;
  float* s3v    = bias1 + 384;
  int* hist     = (int*)(ws + 34179072);                         // 256 KB used
  int* rs       = (int*)(ws + 36538368);                         // 64K+1 ints used
  int* cursor   = (int*)(ws + 38897920);                         // 256 KB used
  int* bsum     = (int*)(ws + 41257216);                         // 4 KB
  int* bsumx    = (int*)(ws + 41261312);                         // 4 KB
  int* bsumT    = (int*)(ws + 41265408);                         // 16 B
  int* sorted   = (int*)(ws + 41265664);                         // 2.36 MB packed keys

  const int* srcp = ei;
  const int* dstp = ei + NEDGE;

  prep_all<<<5377, 256, 0, stream>>>(x, xb, W1, W2, W3,
                                     b1, g1, be1, rm1, rv1,
                                     b2, g2, be2, rm2, rv2,
                                     b3, g3, be3, rm3, rv3,
                                     Wt1, Wt2, bias1, bias2, bias3, s3v, hist);
  hist_k<<<NEDGE/256, 256, 0, stream>>>(dstp, hist);
  scan1_k<<<N_NODES/1024, 256, 0, stream>>>(hist, rs, bsum);     // 64 blocks
  scan1_k<<<1, 256, 0, stream>>>(bsum, bsumx, bsumT);            // scan 64 block sums (tail garbage harmless)
  scan3_k<<<N_NODES/256, 256, 0, stream>>>(rs, bsumx, cursor);   // 256 blocks
  scatter_k<<<NEDGE/256, 256, 0, stream>>>(srcp, dstp, sel, cursor, sorted);

  layer_k<0><<<2048, 256, 0, stream>>>(xb, nullptr, Wt1, nullptr, rs, sorted,
                                       bias1, nullptr, nullptr, h1, nullptr);
  layer_k<1><<<2048, 256, 0, stream>>>(h1, xb, Wt2, Wt1 + 1152*128, rs, sorted,
                                       bias2, bias3, s3v, nullptr, (float*)d_out);
}